// Round 7
// baseline (137.368 us; speedup 1.0000x reference)
//
#include <hip/hip_runtime.h>

// ---------------------------------------------------------------------------
// R20: conv1 + conv2 + conv3 ALL via mfma_f32_16x16x32_f16; fc1/fc2 VALU.
// vs R19 (conv3 was VALU): cut ISSUE-PORT load, not just VALU-flops —
//  - conv3 -> MFMA (23 ksteps, B3g fragments, bw3 hi/lo in k-slots 8/9);
//    deletes the 15x(6 ds + ~20 VALU) loop AND the V3G s_load drains.
//  - validity logic deleted everywhere: the tail fake-tap (tap 9/45) reads
//    OFFSET 0 (live finite record) and its B-fragment is ZERO in prep ->
//    contribution is exactly 0. No cndmask, no ZERO block, no pad init.
//  - SLU2 -> SP2 (silu pairs u32) so conv3 A-silu half is one b32 read.
// im2col fragments (verified by R19 pass): A[row=lane&15][k=(lane>>4)*8+j];
// kstep s covers taps (2s, 2s+1); k-chunks: {basis 2s | silu 2s | basis 2s+1
// | silu 2s+1}. B[k][col=lane&15] prepacked; C: col=lane&15, row=hi4*4+r.
// LDS pool (23,680B, 6 blocks/CU), alias schedule:
//   P1  RECB 784x16B [0,12544) + INSP 784x4B [12544,15680)
//   P2  WRES f16 5x676 [16900,23660)            (reads RECB/INSP)
//   P3  H1B 845x16B [0,13520) + H1SP 845x4B [13520,16900)  (reads WRES)
//   P4  C2 f32 5x128 [16900,19460)              (reads H1B/H1SP)
//   P5  H2B 605x16B [0,9680) + SP2 605x4B [9680,12100)     (reads C2)
//   P6  H3F [16900,17548)                       (reads H2B/SP2)
//   HPK [17552,17888) | RED [17888,18048) | fc1out BASF [0,2048)
// ---------------------------------------------------------------------------

typedef _Float16 h2 __attribute__((ext_vector_type(2)));
typedef _Float16 f16x8 __attribute__((ext_vector_type(8)));
typedef float f32x4 __attribute__((ext_vector_type(4)));

union U4H { uint4 u; f16x8 h; };

__device__ __forceinline__ h2 u2h(unsigned int u) {
  union { unsigned int x; h2 h; } v; v.x = u; return v.h;
}
__device__ __forceinline__ unsigned short f2h_bits(float x) {
  union { _Float16 h; unsigned short u; } v; v.h = (_Float16)x; return v.u;
}
__device__ __forceinline__ float h2f(unsigned short u) {
  union { unsigned short u; _Float16 h; } v; v.u = u; return (float)v.h;
}
__device__ __forceinline__ unsigned int pack2h(float a, float b) {
  return (unsigned int)f2h_bits(a) | ((unsigned int)f2h_bits(b) << 16);
}
__device__ __forceinline__ float fdot2(h2 a, h2 b, float c) {
  return __builtin_amdgcn_fdot2(a, b, c, false);
}

// tap -> record offset; tap out of range (the tail fake tap) -> 0 (live
// record; killed by B=0 in the prepacked fragment).
__device__ __forceinline__ constexpr int off1t(int t) {
  return (t >= 9) ? 0 : (t / 3) * 28 + (t % 3);
}
__device__ __forceinline__ constexpr int off2t(int t) {
  return (t >= 45) ? 0 : (t / 9) * 169 + ((t % 9) / 3) * 13 + (t % 9) % 3;
}
__device__ __forceinline__ constexpr int off3t(int t) {
  return (t >= 45) ? 0 : (t / 9) * 121 + ((t % 9) / 3) * 11 + (t % 9) % 3;
}

// Basis window (8 f16 packed in uint4) + silu, all in registers.
__device__ __forceinline__ void featurize_regs(float v, uint4& bs, float& silu) {
  silu = v / (1.0f + __expf(-v));
  bs.x = 0u; bs.y = 0u; bs.z = 0u; bs.w = 0u;
  float u = fmaf(v, 2.5f, 5.5f);
  if (u >= 0.0f && u < 11.0f) {
    float tf = floorf(u);
    float f = u - tf, f2 = f * f, f3 = f2 * f, om = 1.0f - f;
    const float c6 = 1.0f / 6.0f;
    float w0 = om * om * om * c6;
    float w1 = (3.0f * f3 - 6.0f * f2 + 4.0f) * c6;
    float w2 = (-3.0f * f3 + 3.0f * f2 + 3.0f * f + 1.0f) * c6;
    float w3 = f3 * c6;
    unsigned long long w01 =
        (unsigned long long)f2h_bits(w0) |
        ((unsigned long long)f2h_bits(w1) << 16) |
        ((unsigned long long)f2h_bits(w2) << 32) |
        ((unsigned long long)f2h_bits(w3) << 48);
    int t = (int)tf;                 // 0..10; window starts at slot t-3
    int s = 16 * t - 48;             // bit shift into 128-bit field
    unsigned long long lo, hi;
    if (s >= 0) {
      lo = (s < 64) ? (w01 << s) : 0ull;
      hi = (s == 0) ? 0ull : ((s < 64) ? (w01 >> (64 - s)) : (w01 << (s - 64)));
    } else {
      lo = w01 >> (-s);
      hi = 0ull;
    }
    bs.x = (unsigned int)lo; bs.y = (unsigned int)(lo >> 32);
    bs.z = (unsigned int)hi; bs.w = (unsigned int)(hi >> 32);
  }
}

// ---------------- prep: B-fragments (conv1/2/3) + W1p4 + W2p ---------------
__global__ __launch_bounds__(256) void k_prep(
    const float* __restrict__ bw1, const float* __restrict__ sw1,
    const float* __restrict__ bw2, const float* __restrict__ sw2,
    const float* __restrict__ bw3, const float* __restrict__ sw3,
    const float* __restrict__ w1, const float* __restrict__ w2,
    unsigned int* __restrict__ Bc1g, unsigned int* __restrict__ B2g,
    unsigned int* __restrict__ B3g,
    unsigned int* __restrict__ W1p4, float* __restrict__ W2p) {
  int t = blockIdx.x * 256 + threadIdx.x;
  // Bc1g: 5 ksteps x 64 lanes x 4 dwords, fragment order.
  if (t < 1280) {
    int i = t & 3, l = (t >> 2) & 63, s = t >> 8;
    int k = s * 32 + ((l >> 4) & 3) * 8 + 2 * i;
    int col = l & 15, tap = k >> 4, slot = k & 15;
    unsigned int v = 0u;
    if (col < 5 && tap < 9) {
      if (slot < 8) {
        const float* sp = sw1 + (col * 9 + tap) * 8 + slot;
        v = pack2h(sp[0], sp[1]);
      } else if (slot == 8) {
        float bv = bw1[col * 9 + tap];
        float hi = (float)(_Float16)bv;
        v = pack2h(hi, bv - hi);
      }
    }
    Bc1g[t] = v;
  }
  // B2g: 23 ksteps x 64 lanes x 4 dwords.
  if (t < 5888) {
    int i = t & 3, l = (t >> 2) & 63, s = t >> 8;
    int k = s * 32 + ((l >> 4) & 3) * 8 + 2 * i;
    int col = l & 15, tap = k >> 4, slot = k & 15;
    unsigned int v = 0u;
    if (col < 5 && tap < 45) {
      if (slot < 8) {
        const float* sp = sw2 + (col * 45 + tap) * 8 + slot;
        v = pack2h(sp[0], sp[1]);
      } else if (slot == 8) {
        float bv = bw2[col * 45 + tap];
        float hi = (float)(_Float16)bv;
        v = pack2h(hi, bv - hi);
      }
    }
    B2g[t] = v;
  }
  // B3g: 23 ksteps x 64 lanes x 4 dwords (N-cols 0..1 used).
  if (t < 5888) {
    int i = t & 3, l = (t >> 2) & 63, s = t >> 8;
    int k = s * 32 + ((l >> 4) & 3) * 8 + 2 * i;
    int col = l & 15, tap = k >> 4, slot = k & 15;
    unsigned int v = 0u;
    if (col < 2 && tap < 45) {
      if (slot < 8) {
        const float* sp = sw3 + (col * 45 + tap) * 8 + slot;
        v = pack2h(sp[0], sp[1]);
      } else if (slot == 8) {
        float bv = bw3[col * 45 + tap];
        float hi = (float)(_Float16)bv;
        v = pack2h(hi, bv - hi);
      }
    }
    B3g[t] = v;
  }
  if (t < 43008) {  // W1p4[((g*512)+o)*4+j]: j-th k-pair of group g, out o
    int j = t & 3, o = (t >> 2) & 511, g = t >> 11;
    int kp = g * 4 + j;
    W1p4[t] = (o < 500 && kp < 81)
                  ? pack2h(w1[o * 162 + 2 * kp], w1[o * 162 + 2 * kp + 1])
                  : 0u;
  }
  if (t < 5120) {   // W2p[10][512] zero-padded
    int o = t >> 9, k = t & 511;
    W2p[t] = (k < 500) ? w2[o * 500 + k] : 0.0f;
  }
}

// ---------------- the fused per-image kernel (four waves per block) ---------
__global__ __launch_bounds__(256, 6) void k_fused(
    const float* __restrict__ x,
    const unsigned int* __restrict__ Bc1g, const unsigned int* __restrict__ B2g,
    const unsigned int* __restrict__ B3g,
    const unsigned int* __restrict__ W1p4, const float* __restrict__ W2p,
    const float* __restrict__ b1, const float* __restrict__ b2,
    float* __restrict__ out) {
  __shared__ __attribute__((aligned(16))) char pool[23680];
  uint4*          RECB = (uint4*)pool;                          // 784 x 16B
  unsigned int*   INSP = (unsigned int*)(pool + 12544);         // 784 x 4B
  uint4*          H1B  = (uint4*)pool;                          // 845 x 16B
  unsigned int*   H1SP = (unsigned int*)(pool + 13520);         // 845 x 4B
  unsigned short* WRES = (unsigned short*)(pool + 16900);       // 3380 f16
  float*          C2   = (float*)(pool + 16900);                // 640 f32
  uint4*          H2B  = (uint4*)pool;                          // 605 x 16B
  unsigned int*   SP2  = (unsigned int*)(pool + 9680);          // 605 x 4B
  float*          H3F  = (float*)(pool + 16900);                // 162 f32
  unsigned int*   HPK  = (unsigned int*)(pool + 17552);         // 84 u32
  float*          RED  = (float*)(pool + 17888);                // 40 f32
  float*          BASF = (float*)pool;                          // fc1out 512

  const int b   = blockIdx.x;
  const int tid = threadIdx.x;             // 0..255, four waves
  const int lane = tid & 63;
  const int wv   = tid >> 6;
  const int col  = lane & 15;              // MFMA N-col / A-row lane id
  const int hi4  = lane >> 4;              // 0..3 (k-chunk group)
  const int haf  = hi4 & 1;                // 0: basis half, 1: silu half
  const int par  = hi4 >> 1;               // 0: even tap, 1: odd tap

  // P1: featurize input image -> REC_B (basis) + IN_SP (silu,silu pair)
  #pragma unroll 1
  for (int l = tid; l < 784; l += 256) {
    uint4 bs; float sl;
    featurize_regs(x[b * 784 + l], bs, sl);
    RECB[l] = bs; INSP[l] = pack2h(sl, sl);
  }
  __syncthreads();

  // P2: conv1 via MFMA. M=676 windows (43 tiles), K=144 (5 ksteps of 32).
  {
    U4H B1[5];
    #pragma unroll
    for (int s = 0; s < 5; ++s)
      B1[s].u = ((const uint4*)Bc1g)[s * 64 + lane];
    int mt0 = wv * 11;
    int mtn = (wv < 3) ? 11 : 10;
    #pragma unroll 1
    for (int m = 0; m < mtn; ++m) {
      int mt = mt0 + m;
      int w = mt * 16 + col;
      int wc = (w < 676) ? w : 675;        // clamp addr; write guarded
      int wy = wc / 26;
      int wbase = wy * 28 + (wc - wy * 26);
      f32x4 acc = {0.f, 0.f, 0.f, 0.f};
      #pragma unroll
      for (int s = 0; s < 5; ++s) {
        int ro = par ? off1t(2 * s + 1) : off1t(2 * s);
        U4H a;
        if (haf == 0) {
          a.u = RECB[wbase + ro];
        } else {
          a.u.x = INSP[wbase + ro]; a.u.y = 0u; a.u.z = 0u; a.u.w = 0u;
        }
        acc = __builtin_amdgcn_mfma_f32_16x16x32_f16(a.h, B1[s].h, acc, 0, 0, 0);
      }
      if (col < 5) {
        #pragma unroll
        for (int r = 0; r < 4; ++r) {
          int wr = mt * 16 + hi4 * 4 + r;
          if (wr < 676) WRES[col * 676 + wr] = f2h_bits(acc[r]);
        }
      }
    }
  }
  __syncthreads();  // conv1 A-reads + WRES writes complete

  // P3: 2x2 maxpool + featurize -> H1B/H1SP (aliases input; disjoint WRES)
  if (tid < 169) {
    int py = tid / 13, px = tid - (tid / 13) * 13;
    int w00 = py * 52 + px * 2;            // (2py)*26 + 2px (even)
    const unsigned int* W32 = (const unsigned int*)WRES;
    #pragma unroll
    for (int o = 0; o < 5; ++o) {
      unsigned int a = W32[(o * 676 + w00) >> 1];
      unsigned int c = W32[(o * 676 + w00 + 26) >> 1];
      float v = fmaxf(fmaxf(h2f((unsigned short)a), h2f((unsigned short)(a >> 16))),
                      fmaxf(h2f((unsigned short)c), h2f((unsigned short)(c >> 16))));
      uint4 bs; float sl;
      featurize_regs(v, bs, sl);
      H1B[o * 169 + tid] = bs;
      H1SP[o * 169 + tid] = pack2h(sl, sl);
    }
  }
  __syncthreads();

  // P4: conv2 via MFMA. M=121 (8 tiles, 2/wave), K=720 (23 ksteps).
  {
    int p0 = (wv * 2) * 16 + col;
    int p1 = (wv * 2 + 1) * 16 + col;
    int pc0 = (p0 < 121) ? p0 : 120;
    int pc1 = (p1 < 121) ? p1 : 120;
    int y0 = pc0 / 11, pb0 = y0 * 13 + (pc0 - y0 * 11);
    int y1 = pc1 / 11, pb1 = y1 * 13 + (pc1 - y1 * 11);
    f32x4 ac0 = {0.f, 0.f, 0.f, 0.f}, ac1 = {0.f, 0.f, 0.f, 0.f};
    #pragma unroll
    for (int s = 0; s < 23; ++s) {
      int ro = par ? off2t(2 * s + 1) : off2t(2 * s);
      U4H bf; bf.u = ((const uint4*)B2g)[s * 64 + lane];
      U4H a0, a1;
      if (haf == 0) {
        a0.u = H1B[pb0 + ro]; a1.u = H1B[pb1 + ro];
      } else {
        a0.u.x = H1SP[pb0 + ro]; a0.u.y = 0u; a0.u.z = 0u; a0.u.w = 0u;
        a1.u.x = H1SP[pb1 + ro]; a1.u.y = 0u; a1.u.z = 0u; a1.u.w = 0u;
      }
      ac0 = __builtin_amdgcn_mfma_f32_16x16x32_f16(a0.h, bf.h, ac0, 0, 0, 0);
      ac1 = __builtin_amdgcn_mfma_f32_16x16x32_f16(a1.h, bf.h, ac1, 0, 0, 0);
    }
    if (col < 5) {
      #pragma unroll
      for (int r = 0; r < 4; ++r) {
        C2[col * 128 + (wv * 2) * 16 + hi4 * 4 + r]     = ac0[r];
        C2[col * 128 + (wv * 2 + 1) * 16 + hi4 * 4 + r] = ac1[r];
      }
    }
  }
  __syncthreads();  // conv2 A-reads + C2 dump complete

  // P5: featurize h2 -> H2B/SP2 (alias H1; disjoint C2)
  #pragma unroll 1
  for (int k2 = 0; k2 < 3; ++k2) {
    int it = tid + 256 * k2;
    if (it < 605) {
      int o = it / 121, p = it - o * 121;
      uint4 bs; float sl;
      featurize_regs(C2[o * 128 + p], bs, sl);
      H2B[o * 121 + p] = bs;
      SP2[o * 121 + p] = pack2h(sl, sl);
    }
  }
  __syncthreads();

  // P6: conv3 via MFMA. M=81 -> 6 tiles: wave wv does tile wv (+ wv+4 for
  // wv<2). N-cols 0..1 = output channels.
  {
    #pragma unroll 1
    for (int pass = 0; pass < 2; ++pass) {
      if (pass == 1 && wv >= 2) break;     // wave-uniform
      int mt = (pass == 0) ? wv : (wv + 4);
      int pos = mt * 16 + col;
      int pc = (pos < 81) ? pos : 80;
      int y0 = pc / 9;
      int pb = y0 * 11 + (pc - y0 * 9);
      f32x4 acc = {0.f, 0.f, 0.f, 0.f};
      #pragma unroll
      for (int s = 0; s < 23; ++s) {
        int ro = par ? off3t(2 * s + 1) : off3t(2 * s);
        U4H bf; bf.u = ((const uint4*)B3g)[s * 64 + lane];
        U4H a;
        if (haf == 0) {
          a.u = H2B[pb + ro];
        } else {
          a.u.x = SP2[pb + ro]; a.u.y = 0u; a.u.z = 0u; a.u.w = 0u;
        }
        acc = __builtin_amdgcn_mfma_f32_16x16x32_f16(a.h, bf.h, acc, 0, 0, 0);
      }
      if (col < 2) {
        #pragma unroll
        for (int r = 0; r < 4; ++r) {
          int pr = mt * 16 + hi4 * 4 + r;
          if (pr < 81) H3F[col * 81 + pr] = acc[r];
        }
      }
    }
  }
  __syncthreads();
  if (tid < 84)
    HPK[tid] = (tid < 81) ? pack2h(H3F[2 * tid], H3F[2 * tid + 1]) : 0u;
  __syncthreads();

  // P7: fc1 (162->500) + bias + ReLU; 2 outs/lane; double-buffered global
  float fa[2] = {0.0f, 0.0f};
  {
    const uint4* hp4 = (const uint4*)HPK;
    const uint4* wbase = (const uint4*)W1p4 + tid;
    uint4 wA[2], wB[2];
    #pragma unroll
    for (int i = 0; i < 2; ++i) wA[i] = wbase[i * 256];   // group 0
    #pragma unroll 1
    for (int g = 0; g < 21; g += 2) {
      if (g + 1 < 21) {
        const uint4* p = wbase + (g + 1) * 512;
        #pragma unroll
        for (int i = 0; i < 2; ++i) wB[i] = p[i * 256];
      }
      {
        uint4 hk = hp4[g];
        #pragma unroll
        for (int i = 0; i < 2; ++i) {
          float a = fa[i];
          a = fdot2(u2h(hk.x), u2h(wA[i].x), a);
          a = fdot2(u2h(hk.y), u2h(wA[i].y), a);
          a = fdot2(u2h(hk.z), u2h(wA[i].z), a);
          a = fdot2(u2h(hk.w), u2h(wA[i].w), a);
          fa[i] = a;
        }
      }
      if (g + 2 < 21) {
        const uint4* p = wbase + (g + 2) * 512;
        #pragma unroll
        for (int i = 0; i < 2; ++i) wA[i] = p[i * 256];
      }
      if (g + 1 < 21) {
        uint4 hk = hp4[g + 1];
        #pragma unroll
        for (int i = 0; i < 2; ++i) {
          float a = fa[i];
          a = fdot2(u2h(hk.x), u2h(wB[i].x), a);
          a = fdot2(u2h(hk.y), u2h(wB[i].y), a);
          a = fdot2(u2h(hk.z), u2h(wB[i].z), a);
          a = fdot2(u2h(hk.w), u2h(wB[i].w), a);
          fa[i] = a;
        }
      }
    }
  }
  #pragma unroll
  for (int i = 0; i < 2; ++i) {
    int o = tid + 256 * i;
    float bb = (o < 500) ? b1[o] : 0.0f;
    float v = fa[i] + bb;
    BASF[o] = (v > 0.0f && o < 500) ? v : 0.0f;  // fc1out (alias H2B, dead)
  }
  __syncthreads();

  // P8: fc2 (500->10): lane covers k = 2*tid..2*tid+1, shfl + LDS reduction
  float acc10[10];
  {
    float2 ha = ((const float2*)BASF)[tid];
    #pragma unroll
    for (int o = 0; o < 10; ++o) {
      float2 w = ((const float2*)&W2p[o * 512])[tid];
      acc10[o] = ha.x * w.x + ha.y * w.y;
    }
  }
  #pragma unroll
  for (int off = 32; off > 0; off >>= 1) {
    #pragma unroll
    for (int o = 0; o < 10; ++o) acc10[o] += __shfl_down(acc10[o], off);
  }
  if ((tid & 63) == 0) {
    int wid = tid >> 6;
    #pragma unroll
    for (int o = 0; o < 10; ++o) RED[wid * 10 + o] = acc10[o];
  }
  __syncthreads();
  if (tid < 10)
    out[b * 10 + tid] = RED[tid] + RED[10 + tid] + RED[20 + tid] + RED[30 + tid] + b2[tid];
}

// ---------------------------------------------------------------------------
extern "C" void kernel_launch(void* const* d_in, const int* in_sizes, int n_in,
                              void* d_out, int out_size, void* d_ws, size_t ws_size,
                              hipStream_t stream) {
  (void)in_sizes; (void)n_in; (void)out_size; (void)ws_size;
  const float* x   = (const float*)d_in[0];
  const float* bw1 = (const float*)d_in[1];
  const float* sw1 = (const float*)d_in[2];
  const float* bw2 = (const float*)d_in[3];
  const float* sw2 = (const float*)d_in[4];
  const float* bw3 = (const float*)d_in[5];
  const float* sw3 = (const float*)d_in[6];
  const float* w1  = (const float*)d_in[7];
  const float* b1  = (const float*)d_in[8];
  const float* w2  = (const float*)d_in[9];
  const float* b2  = (const float*)d_in[10];
  float* out = (float*)d_out;

  char* ws = (char*)d_ws;
  unsigned int* Bc1g = (unsigned int*)(ws);            // 1,280 u  (5,120 B)
  unsigned int* B2g  = (unsigned int*)(ws + 5120);     // 5,888 u  (23,552 B)
  unsigned int* B3g  = (unsigned int*)(ws + 28672);    // 5,888 u  (23,552 B)
  float*        W2p  = (float*)(ws + 52224);           // 5,120 f  (20,480 B)
  unsigned int* W1p4 = (unsigned int*)(ws + 73728);    // 43,008 u (172,032 B)

  k_prep<<<168, 256, 0, stream>>>(bw1, sw1, bw2, sw2, bw3, sw3, w1, w2,
                                  Bc1g, B2g, B3g, W1p4, W2p);
  k_fused<<<2048, 256, 0, stream>>>(x, Bc1g, B2g, B3g,
                                    W1p4, W2p, b1, b2, out);
}

// Round 8
// 127.518 us; speedup vs baseline: 1.0772x; 1.0772x over previous
//
#include <hip/hip_runtime.h>

// ---------------------------------------------------------------------------
// R21 = R18 (best measured: 58.4us) + two surgical fixes. MFMA experiments
// (R19/R20) were neutral-to-negative — reverted entirely.
//  - conv1 PARITY SWIZZLE: input records stored with even cols at 0..13,
//    odd cols at 14..27 per row. Pool-window ds_read_b128 become stride-16B
//    (was stride-32B = 4-way bank conflict ~2-3M cycles). kx unrolled so the
//    parity column-select is compile-time; per-ky reads dedupe 12 -> 8.
//  - silu via __builtin_amdgcn_rcpf (kills ~10-inst exact-div sequence per
//    featurize; tolerance 2e-3 >> rcp error).
//  - conv2/conv3: R18 unchanged (og-contiguous weights, s_load/SGPR path).
//  - weights stay GLOBAL (R16 proved LDS-weights spill catastrophically).
// Cardinal cubic B-spline: basis_j(x) = B3(u - j), u = 2.5x+5.5 (4 taps).
// ---------------------------------------------------------------------------

typedef _Float16 h2 __attribute__((ext_vector_type(2)));

__device__ __forceinline__ h2 u2h(unsigned int u) {
  union { unsigned int x; h2 h; } v; v.x = u; return v.h;
}
__device__ __forceinline__ unsigned short f2h_bits(float x) {
  union { _Float16 h; unsigned short u; } v; v.h = (_Float16)x; return v.u;
}
__device__ __forceinline__ float h2f(unsigned short u) {
  union { unsigned short u; _Float16 h; } v; v.u = u; return (float)v.h;
}
__device__ __forceinline__ unsigned int pack2h(float a, float b) {
  return (unsigned int)f2h_bits(a) | ((unsigned int)f2h_bits(b) << 16);
}
__device__ __forceinline__ float fdot2(h2 a, h2 b, float c) {
  return __builtin_amdgcn_fdot2(a, b, c, false);
}

// Basis window (8 f16 packed in uint4) + silu, all in registers.
__device__ __forceinline__ void featurize_regs(float v, uint4& bs, float& silu) {
  silu = v * __builtin_amdgcn_rcpf(1.0f + __expf(-v));
  bs.x = 0u; bs.y = 0u; bs.z = 0u; bs.w = 0u;
  float u = fmaf(v, 2.5f, 5.5f);
  if (u >= 0.0f && u < 11.0f) {
    float tf = floorf(u);
    float f = u - tf, f2 = f * f, f3 = f2 * f, om = 1.0f - f;
    const float c6 = 1.0f / 6.0f;
    float w0 = om * om * om * c6;
    float w1 = (3.0f * f3 - 6.0f * f2 + 4.0f) * c6;
    float w2 = (-3.0f * f3 + 3.0f * f2 + 3.0f * f + 1.0f) * c6;
    float w3 = f3 * c6;
    unsigned long long w01 =
        (unsigned long long)f2h_bits(w0) |
        ((unsigned long long)f2h_bits(w1) << 16) |
        ((unsigned long long)f2h_bits(w2) << 32) |
        ((unsigned long long)f2h_bits(w3) << 48);
    int t = (int)tf;                 // 0..10; window starts at slot t-3
    int s = 16 * t - 48;             // bit shift into 128-bit field
    unsigned long long lo, hi;
    if (s >= 0) {
      lo = (s < 64) ? (w01 << s) : 0ull;
      hi = (s == 0) ? 0ull : ((s < 64) ? (w01 >> (64 - s)) : (w01 << (s - 64)));
    } else {
      lo = w01 >> (-s);
      hi = 0ull;
    }
    bs.x = (unsigned int)lo; bs.y = (unsigned int)(lo >> 32);
    bs.z = (unsigned int)hi; bs.w = (unsigned int)(hi >> 32);
  }
}

// KAN 3x3-conv accumulation, one position per lane, NO output channels.
// Weights (wS/wB) are og-contiguous global arrays laid out [cky][kx][j] ->
// one wide s_load per cky row -> SGPR operands.
template <int NO, int CHS, int ROWW>
__device__ __forceinline__ void kconv_plain(
    const uint4* bas, const unsigned short* slu,
    const uint4* __restrict__ wS, const float* __restrict__ wB,
    int y0, int x0, float (&acc)[NO]) {
  const uint4* wp = wS;
  const float* bp = wB;
  int baC = y0 * ROWW + x0;
  #pragma unroll 1
  for (int c = 0; c < 5; ++c) {
    int ba = baC;
    #pragma unroll 1
    for (int ky = 0; ky < 3; ++ky) {
      uint4 q0 = bas[ba], q1 = bas[ba + 1], q2 = bas[ba + 2];
      float s0 = h2f(slu[ba]), s1 = h2f(slu[ba + 1]), s2 = h2f(slu[ba + 2]);
      #pragma unroll
      for (int kx = 0; kx < 3; ++kx) {
        uint4 q = (kx == 0) ? q0 : ((kx == 1) ? q1 : q2);
        float sl = (kx == 0) ? s0 : ((kx == 1) ? s1 : s2);
        h2 a0 = u2h(q.x), a1 = u2h(q.y), a2 = u2h(q.z), a3 = u2h(q.w);
        #pragma unroll
        for (int j = 0; j < NO; ++j) {
          uint4 w = wp[kx * NO + j];
          float a = acc[j];
          a = fdot2(a0, u2h(w.x), a);
          a = fdot2(a1, u2h(w.y), a);
          a = fdot2(a2, u2h(w.z), a);
          a = fdot2(a3, u2h(w.w), a);
          acc[j] = fmaf(sl, bp[kx * NO + j], a);
        }
      }
      wp += 3 * NO; bp += 3 * NO;
      ba += ROWW;
    }
    baC += CHS;
  }
}

// ---------------- prep: conv weights (og-packed) + W1p4 + padded W2 ---------
__global__ __launch_bounds__(256) void k_prep(
    const float* __restrict__ bw1, const float* __restrict__ sw1,
    const float* __restrict__ bw2, const float* __restrict__ sw2,
    const float* __restrict__ bw3, const float* __restrict__ sw3,
    const float* __restrict__ w1, const float* __restrict__ w2,
    unsigned int* __restrict__ V1s, float* __restrict__ V1b,
    unsigned int* __restrict__ V2G0s, float* __restrict__ V2G0b,
    unsigned int* __restrict__ V2G1s, float* __restrict__ V2G1b,
    unsigned int* __restrict__ V3Gs, float* __restrict__ V3Gb,
    unsigned int* __restrict__ W1p4, float* __restrict__ W2p) {
  int t = blockIdx.x * 256 + threadIdx.x;
  if (t < 180) {  // L1: 9 taps x 5 outs x 4 pairs (tap-major, o contiguous)
    int p = t & 3, o = (t >> 2) % 5, in = t / 20;
    V1s[t] = pack2h(sw1[(o * 9 + in) * 8 + 2 * p], sw1[(o * 9 + in) * 8 + 2 * p + 1]);
  }
  if (t < 45)  { int o = t % 5, in = t / 5; V1b[t] = bw1[o * 9 + in]; }
  // L2 og0 (ch 0..2): [cky][kx][j<3] uint4 -> 540 words
  if (t < 540) {
    int p = t & 3, u4 = t >> 2;
    int j = u4 % 3, kx = (u4 / 3) % 3, cky = u4 / 9;
    int in = (cky / 3) * 9 + (cky % 3) * 3 + kx;
    V2G0s[t] = pack2h(sw2[(j * 45 + in) * 8 + 2 * p], sw2[(j * 45 + in) * 8 + 2 * p + 1]);
  }
  if (t < 135) {  // og0 biases
    int j = t % 3, kx = (t / 3) % 3, cky = t / 9;
    int in = (cky / 3) * 9 + (cky % 3) * 3 + kx;
    V2G0b[t] = bw2[j * 45 + in];
  }
  // L2 og1 (ch 3..4): [cky][kx][j<2] uint4 -> 360 words
  if (t < 360) {
    int p = t & 3, u4 = t >> 2;
    int j = u4 % 2, kx = (u4 / 2) % 3, cky = u4 / 6;
    int o = 3 + j;
    int in = (cky / 3) * 9 + (cky % 3) * 3 + kx;
    V2G1s[t] = pack2h(sw2[(o * 45 + in) * 8 + 2 * p], sw2[(o * 45 + in) * 8 + 2 * p + 1]);
  }
  if (t < 90) {   // og1 biases
    int j = t % 2, kx = (t / 2) % 3, cky = t / 6;
    int o = 3 + j;
    int in = (cky / 3) * 9 + (cky % 3) * 3 + kx;
    V2G1b[t] = bw2[o * 45 + in];
  }
  // L3: [ou][cky][kx] uint4 -> 360 words
  if (t < 360) {
    int p = t & 3, u4 = t >> 2;
    int kx = u4 % 3, cky = (u4 / 3) % 15, ou = u4 / 45;
    int in = (cky / 3) * 9 + (cky % 3) * 3 + kx;
    V3Gs[t] = pack2h(sw3[(ou * 45 + in) * 8 + 2 * p], sw3[(ou * 45 + in) * 8 + 2 * p + 1]);
  }
  if (t < 90) {
    int kx = t % 3, cky = (t / 3) % 15, ou = t / 45;
    int in = (cky / 3) * 9 + (cky % 3) * 3 + kx;
    V3Gb[t] = bw3[ou * 45 + in];
  }
  if (t < 43008) {  // W1p4[((g*512)+o)*4+j]: j-th k-pair of group g, out o
    int j = t & 3, o = (t >> 2) & 511, g = t >> 11;
    int kp = g * 4 + j;
    W1p4[t] = (o < 500 && kp < 81)
                  ? pack2h(w1[o * 162 + 2 * kp], w1[o * 162 + 2 * kp + 1])
                  : 0u;
  }
  if (t < 5120) {   // W2p[10][512] zero-padded
    int o = t >> 9, k = t & 511;
    W2p[t] = (k < 500) ? w2[o * 500 + k] : 0.0f;
  }
}

// ---------------- the fused per-image kernel (four waves per block) ---------
__global__ __launch_bounds__(256, 8) void k_fused(
    const float* __restrict__ x,
    const unsigned int* __restrict__ V1s, const float* __restrict__ V1b,
    const unsigned int* __restrict__ V2G0s, const float* __restrict__ V2G0b,
    const unsigned int* __restrict__ V2G1s, const float* __restrict__ V2G1b,
    const unsigned int* __restrict__ V3Gs, const float* __restrict__ V3Gb,
    const unsigned int* __restrict__ W1p4, const float* __restrict__ W2p,
    const float* __restrict__ b1, const float* __restrict__ b2,
    float* __restrict__ out) {
  __shared__ uint4 bas[845];               // 13,520 B
  __shared__ unsigned short slu16[848];    //  1,696 B
  __shared__ float red[40];                // fc2 cross-wave scratch
  float*        basF = (float*)bas;        // dword view of bas
  float*        h3f  = basF + 2048;        // h3 (162 f), dead-by-order region
  unsigned int* hpk  = (unsigned int*)basF + 2560;  // 84 uints
  const int b = blockIdx.x;
  const int tid = threadIdx.x;             // 0..255, four waves

  // P1: featurize input image (784 px), PARITY-SWIZZLED columns:
  //   col xx stored at (xx&1)*14 + (xx>>1)  -> conv1 reads stride-16B
  #pragma unroll 1
  for (int l = tid; l < 784; l += 256) {
    uint4 bs; float sl;
    featurize_regs(x[b * 784 + l], bs, sl);
    int y = l / 28, xx = l - y * 28;
    int idx = y * 28 + ((xx & 1) ? 14 : 0) + (xx >> 1);
    bas[idx] = bs; slu16[idx] = f2h_bits(sl);
  }
  __syncthreads();

  // P2: conv1 (1->5) + 2x2 maxpool; one pooled output per lane (tid<169).
  // Per ky: 8 dedup'd parity reads (rows ky,ky+1; parity-cols E0,O0,E1,O1),
  // kx UNROLLED (parity col-select compile-time):
  //   kx=0 -> (E0,O0)  kx=1 -> (O0,E1)  kx=2 -> (E1,O1)
  float h1v[5];
  if (tid < 169) {
    int py = tid / 13, px = tid % 13;
    float wacc[4][5];
    #pragma unroll
    for (int wi = 0; wi < 4; ++wi)
      #pragma unroll
      for (int o = 0; o < 5; ++o) wacc[wi][o] = 0.0f;
    #pragma unroll 1
    for (int ky = 0; ky < 3; ++ky) {
      int rA = (2 * py + ky) * 28 + px;
      uint4 q[2][4]; float sl[2][4];
      #pragma unroll
      for (int r = 0; r < 2; ++r) {
        int base = rA + r * 28;
        q[r][0] = bas[base];      sl[r][0] = h2f(slu16[base]);       // E0
        q[r][1] = bas[base + 14]; sl[r][1] = h2f(slu16[base + 14]);  // O0
        q[r][2] = bas[base + 1];  sl[r][2] = h2f(slu16[base + 1]);   // E1
        q[r][3] = bas[base + 15]; sl[r][3] = h2f(slu16[base + 15]);  // O1
      }
      const unsigned int* wrow = V1s + ky * 60;
      const float* brow = V1b + ky * 15;
      #pragma unroll
      for (int kx = 0; kx < 3; ++kx) {
        const int cA = (kx == 0) ? 0 : ((kx == 1) ? 1 : 2);
        const int cB = (kx == 0) ? 1 : ((kx == 1) ? 2 : 3);
        const unsigned int* wp = wrow + kx * 20;
        const float* bp = brow + kx * 5;
        #pragma unroll
        for (int dy = 0; dy < 2; ++dy) {
          #pragma unroll
          for (int dx = 0; dx < 2; ++dx) {
            const int ci = dx ? cB : cA;
            uint4 qq = q[dy][ci];
            float s = sl[dy][ci];
            h2 a0 = u2h(qq.x), a1 = u2h(qq.y), a2 = u2h(qq.z), a3 = u2h(qq.w);
            #pragma unroll
            for (int o = 0; o < 5; ++o) {
              float a = wacc[dy * 2 + dx][o];
              a = fdot2(a0, u2h(wp[o * 4 + 0]), a);
              a = fdot2(a1, u2h(wp[o * 4 + 1]), a);
              a = fdot2(a2, u2h(wp[o * 4 + 2]), a);
              a = fdot2(a3, u2h(wp[o * 4 + 3]), a);
              wacc[dy * 2 + dx][o] = fmaf(s, bp[o], a);
            }
          }
        }
      }
    }
    #pragma unroll
    for (int o = 0; o < 5; ++o)
      h1v[o] = fmaxf(fmaxf(wacc[0][o], wacc[1][o]),
                     fmaxf(wacc[2][o], wacc[3][o]));
  }
  __syncthreads();  // all conv1 LDS reads (all waves) done
  // write featurized h1 (aliases the input-pixel region; plain layout)
  if (tid < 169) {
    #pragma unroll
    for (int o = 0; o < 5; ++o) {
      uint4 bs; float sl;
      featurize_regs(h1v[o], bs, sl);
      bas[o * 169 + tid] = bs; slu16[o * 169 + tid] = f2h_bits(sl);
    }
  }
  __syncthreads();

  // P4: conv2 (5->5); lanes split by (position, channel-group):
  //   og=0 (waves 0,1): channels 0..2   og=1 (waves 2,3): channels 3..4
  int og = __builtin_amdgcn_readfirstlane(tid >> 7);   // wave-uniform
  int p2 = tid & 127;
  float acc2a[3] = {0.0f, 0.0f, 0.0f};
  float acc2b[2] = {0.0f, 0.0f};
  {
    int pc = (p2 < 121) ? p2 : 120;     // clamp (writeback guarded)
    int y0 = pc / 11, x0 = pc % 11;
    if (og == 0)
      kconv_plain<3, 169, 13>(bas, slu16, (const uint4*)V2G0s, V2G0b, y0, x0, acc2a);
    else
      kconv_plain<2, 169, 13>(bas, slu16, (const uint4*)V2G1s, V2G1b, y0, x0, acc2b);
  }
  __syncthreads();  // all conv2 reads done before h2 overwrites bas
  if (p2 < 121) {
    if (og == 0) {
      #pragma unroll
      for (int j = 0; j < 3; ++j) {
        uint4 bs; float sl;
        featurize_regs(acc2a[j], bs, sl);
        bas[j * 121 + p2] = bs; slu16[j * 121 + p2] = f2h_bits(sl);
      }
    } else {
      #pragma unroll
      for (int j = 0; j < 2; ++j) {
        uint4 bs; float sl;
        featurize_regs(acc2b[j], bs, sl);
        bas[(3 + j) * 121 + p2] = bs; slu16[(3 + j) * 121 + p2] = f2h_bits(sl);
      }
    }
  }
  __syncthreads();

  // P6: conv3 (5->2); lanes split by (position, output):
  //   waves 0,1: out 0   waves 2,3: out 1
  float acc3[1] = {0.0f};
  {
    int pc = (p2 < 81) ? p2 : 80;
    int y0 = pc / 9, x0 = pc - (pc / 9) * 9;
    kconv_plain<1, 121, 11>(bas, slu16, (const uint4*)V3Gs + og * 45,
                            V3Gb + og * 45, y0, x0, acc3);
  }
  __syncthreads();  // all conv3 reads done before h3 overwrites bas region
  if (p2 < 81) h3f[og * 81 + p2] = acc3[0];
  __syncthreads();
  if (tid < 84)
    hpk[tid] = (tid < 81) ? pack2h(h3f[2 * tid], h3f[2 * tid + 1]) : 0u;
  __syncthreads();

  // P7: fc1 (162->500) + bias + ReLU; 2 outs/lane; double-buffered global
  // loads (vmcnt is in-order & separate from LDS lgkmcnt -> real prefetch).
  float fa[2] = {0.0f, 0.0f};
  {
    const uint4* hp4 = (const uint4*)hpk;
    const uint4* wbase = (const uint4*)W1p4 + tid;
    uint4 wA[2], wB[2];
    #pragma unroll
    for (int i = 0; i < 2; ++i) wA[i] = wbase[i * 256];   // group 0
    #pragma unroll 1
    for (int g = 0; g < 21; g += 2) {
      if (g + 1 < 21) {
        const uint4* p = wbase + (g + 1) * 512;
        #pragma unroll
        for (int i = 0; i < 2; ++i) wB[i] = p[i * 256];
      }
      {
        uint4 hk = hp4[g];
        #pragma unroll
        for (int i = 0; i < 2; ++i) {
          float a = fa[i];
          a = fdot2(u2h(hk.x), u2h(wA[i].x), a);
          a = fdot2(u2h(hk.y), u2h(wA[i].y), a);
          a = fdot2(u2h(hk.z), u2h(wA[i].z), a);
          a = fdot2(u2h(hk.w), u2h(wA[i].w), a);
          fa[i] = a;
        }
      }
      if (g + 2 < 21) {
        const uint4* p = wbase + (g + 2) * 512;
        #pragma unroll
        for (int i = 0; i < 2; ++i) wA[i] = p[i * 256];
      }
      if (g + 1 < 21) {
        uint4 hk = hp4[g + 1];
        #pragma unroll
        for (int i = 0; i < 2; ++i) {
          float a = fa[i];
          a = fdot2(u2h(hk.x), u2h(wB[i].x), a);
          a = fdot2(u2h(hk.y), u2h(wB[i].y), a);
          a = fdot2(u2h(hk.z), u2h(wB[i].z), a);
          a = fdot2(u2h(hk.w), u2h(wB[i].w), a);
          fa[i] = a;
        }
      }
    }
  }
  #pragma unroll
  for (int i = 0; i < 2; ++i) {
    int o = tid + 256 * i;
    float bb = (o < 500) ? b1[o] : 0.0f;
    float v = fa[i] + bb;
    basF[o] = (v > 0.0f && o < 500) ? v : 0.0f;  // fc1out[512] in bas[0..127]
  }
  __syncthreads();

  // P8: fc2 (500->10): lane covers k = 2*tid..2*tid+1, shfl + LDS reduction
  float acc10[10];
  {
    float2 ha = ((const float2*)basF)[tid];
    #pragma unroll
    for (int o = 0; o < 10; ++o) {
      float2 w = ((const float2*)&W2p[o * 512])[tid];
      acc10[o] = ha.x * w.x + ha.y * w.y;
    }
  }
  #pragma unroll
  for (int off = 32; off > 0; off >>= 1) {
    #pragma unroll
    for (int o = 0; o < 10; ++o) acc10[o] += __shfl_down(acc10[o], off);
  }
  if ((tid & 63) == 0) {
    int wid = tid >> 6;
    #pragma unroll
    for (int o = 0; o < 10; ++o) red[wid * 10 + o] = acc10[o];
  }
  __syncthreads();
  if (tid < 10)
    out[b * 10 + tid] = red[tid] + red[10 + tid] + red[20 + tid] + red[30 + tid] + b2[tid];
}

// ---------------------------------------------------------------------------
extern "C" void kernel_launch(void* const* d_in, const int* in_sizes, int n_in,
                              void* d_out, int out_size, void* d_ws, size_t ws_size,
                              hipStream_t stream) {
  (void)in_sizes; (void)n_in; (void)out_size; (void)ws_size;
  const float* x   = (const float*)d_in[0];
  const float* bw1 = (const float*)d_in[1];
  const float* sw1 = (const float*)d_in[2];
  const float* bw2 = (const float*)d_in[3];
  const float* sw2 = (const float*)d_in[4];
  const float* bw3 = (const float*)d_in[5];
  const float* sw3 = (const float*)d_in[6];
  const float* w1  = (const float*)d_in[7];
  const float* b1  = (const float*)d_in[8];
  const float* w2  = (const float*)d_in[9];
  const float* b2  = (const float*)d_in[10];
  float* out = (float*)d_out;

  char* ws = (char*)d_ws;
  unsigned int* V1s   = (unsigned int*)(ws);           // 180 u   (720 B)
  float*        V1b   = (float*)(ws + 768);            // 45 f    (180 B)
  unsigned int* V2G0s = (unsigned int*)(ws + 1024);    // 540 u   (2,160 B)
  unsigned int* V2G1s = (unsigned int*)(ws + 3200);    // 360 u   (1,440 B)
  unsigned int* V3Gs  = (unsigned int*)(ws + 4640);    // 360 u   (1,440 B)
  float*        V2G0b = (float*)(ws + 6080);           // 135 f   (540 B)
  float*        V2G1b = (float*)(ws + 6624);           // 90 f    (360 B)
  float*        V3Gb  = (float*)(ws + 6984);           // 90 f    (360 B)
  float*        W2p   = (float*)(ws + 7680);           // 5,120 f (20,480 B)
  unsigned int* W1p4  = (unsigned int*)(ws + 28672);   // 43,008 u (172,032 B)

  k_prep<<<168, 256, 0, stream>>>(bw1, sw1, bw2, sw2, bw3, sw3, w1, w2,
                                  V1s, V1b, V2G0s, V2G0b, V2G1s, V2G1b,
                                  V3Gs, V3Gb, W1p4, W2p);
  k_fused<<<2048, 256, 0, stream>>>(x, V1s, V1b, V2G0s, V2G0b, V2G1s, V2G1b,
                                    V3Gs, V3Gb, W1p4, W2p, b1, b2, out);
}